// Round 16
// baseline (70.653 us; speedup 1.0000x reference)
//
#include <hip/hip_runtime.h>
#include <hip/hip_bf16.h>

#define B_ 4
#define T_ 4096
#define C_ 1024

typedef __bf16 bf16_t;
typedef __bf16 bf16x8 __attribute__((ext_vector_type(8)));
typedef float f32x4 __attribute__((ext_vector_type(4)));

__device__ __forceinline__ void gld16(const void* g, void* l) {
    __builtin_amdgcn_global_load_lds((const __attribute__((address_space(1))) void*)g,
                                     (__attribute__((address_space(3))) void*)l, 16, 0, 0);
}

// ---------------- Kernel A: convert W -> bf16 ----------------
// Wq pre-scaled by 0.125*log2(e): softmax computed base-2 (exactly equivalent).
__global__ void wcvt_kernel(const float* __restrict__ Wq, const float* __restrict__ Wk,
                            const float* __restrict__ Wv, bf16_t* __restrict__ wbf) {
    int i = blockIdx.x * 256 + threadIdx.x;
    int m = i >> 16;
    int r = i & 65535;
    const float* src = (m == 0) ? Wq : (m == 1) ? Wk : Wv;
    float s = (m == 0) ? 0.125f * 1.44269504f : 1.0f;
    wbf[i] = (bf16_t)(src[r] * s);
}

// ---------------- Kernel B: QKV projection v7b — ROLLED loop, pointer rotation -----
// r11's proven structure with a rolled (not unrolled) 16-step main loop: LDS buffers
// rotate as runtime pointers, global srcs advance by constant strides -> ~70-inst
// body, I$-resident. W (L2): 2 bufs, 1-ahead. x (HBM/L3): 3 bufs, 2-ahead.
// Per-step issue = 2 X + 6 W gld16; top-of-step vmcnt(2) drains exactly X(c)+W(c),
// keeps X(c+1) in flight. FIX vs r15: X stages BOTH 16-row halves (2 gld16/thread).
// kb/vtb written PRE-SWIZZLED for the attention kernel.
__global__ __launch_bounds__(256, 2)
void qkv_proj_kernel(const float* __restrict__ x, const bf16_t* __restrict__ wbf,
                     bf16_t* __restrict__ qb, bf16_t* __restrict__ kb,
                     bf16_t* __restrict__ vtb) {
    __shared__ float  xs[3][2048];     // 3 x 8 KB:  [32 rows][64 k] f32, 32B-block XOR swz
    __shared__ bf16_t wsb[2][12288];   // 2 x 24 KB: [192 h][64 k] bf16, 16B-unit XOR swz

    const int tid = threadIdx.x;
    const int w = tid >> 6, lane = tid & 63, lr = lane & 15, kg = lane >> 4;
    const int rg = w & 1, cg = w >> 1;   // row-group (16 rows), col-group (6 pairs)
    const int row0 = blockIdx.x * 32;

    // per-thread global source pointers (advance by constant bytes per step)
    const int xr_ = tid >> 4, xu = tid & 15;           // x stage: row 0..15, 16B-unit
    const char* xg = (const char*)x + (size_t)(row0 + xr_) * 4096
                     + (((xu >> 1) ^ (xr_ & 7)) * 32) + ((xu & 1) * 16);
    const int wh = tid >> 3, wu = tid & 7;             // W stage rows 0..31 (+j*32)
    const char* wg = (const char*)wbf;

    // LDS rotating pointers
    char* xs_c  = (char*)&xs[0][0];
    char* xs_n  = (char*)&xs[1][0];
    char* xs_nn = (char*)&xs[2][0];
    char* ws_c  = (char*)&wsb[0][0];
    char* ws_n  = (char*)&wsb[1][0];

    // rows r and r+16 share (r&7) -> same swizzle; second half at src +64KB, dst +4KB
#define ISSUE_X(kk, dst) {                                                          \
        gld16(xg + (size_t)(kk) * 256,         (dst) + (size_t)tid * 16);           \
        gld16(xg + 65536 + (size_t)(kk) * 256, (dst) + 4096 + (size_t)tid * 16); }
#define ISSUE_W(kk, dst) {                                                          \
        _Pragma("unroll")                                                           \
        for (int j = 0; j < 6; ++j) {                                               \
            int h = wh + j * 32;                                                    \
            gld16(wg + (size_t)h * 2048 + (size_t)(kk) * 128 + ((wu ^ (h & 7)) * 16), \
                  (dst) + (size_t)(tid + j * 256) * 16); } }

    f32x4 acc[6];
    #pragma unroll
    for (int j = 0; j < 6; ++j) acc[j] = (f32x4){0.f, 0.f, 0.f, 0.f};

    ISSUE_X(0, xs_c);
    ISSUE_W(0, ws_c);
    ISSUE_X(1, xs_n);

    const int rl = rg * 16 + lr;
    const int xoff0 = (((kg)     ^ (lr & 7)) * 32);    // byte offsets of 32B x-blocks
    const int xoff1 = (((kg + 4) ^ (lr & 7)) * 32);

    #pragma clang loop unroll(disable)
    for (int c = 0; c < 16; ++c) {
        if (c < 15) {
            asm volatile("s_waitcnt vmcnt(2)" ::: "memory");   // drain X(c)+W(c), keep X(c+1)
        } else {
            asm volatile("s_waitcnt vmcnt(0)" ::: "memory");
        }
        __builtin_amdgcn_s_barrier();
        if (c < 15) ISSUE_W(c + 1, ws_n);
        if (c < 14) ISSUE_X(c + 2, xs_nn);

        // ---- compute step c: x from xs_c, W from ws_c ----
        {
            const char* xrow = xs_c + (size_t)rl * 256;
            float4 a0 = *(const float4*)(xrow + xoff0);
            float4 a1 = *(const float4*)(xrow + xoff0 + 16);
            float4 b0 = *(const float4*)(xrow + xoff1);
            float4 b1 = *(const float4*)(xrow + xoff1 + 16);
            bf16x8 af0, af1;
            af0[0]=(bf16_t)a0.x; af0[1]=(bf16_t)a0.y; af0[2]=(bf16_t)a0.z; af0[3]=(bf16_t)a0.w;
            af0[4]=(bf16_t)a1.x; af0[5]=(bf16_t)a1.y; af0[6]=(bf16_t)a1.z; af0[7]=(bf16_t)a1.w;
            af1[0]=(bf16_t)b0.x; af1[1]=(bf16_t)b0.y; af1[2]=(bf16_t)b0.z; af1[3]=(bf16_t)b0.w;
            af1[4]=(bf16_t)b1.x; af1[5]=(bf16_t)b1.y; af1[6]=(bf16_t)b1.z; af1[7]=(bf16_t)b1.w;

            __builtin_amdgcn_s_setprio(1);
            #pragma unroll
            for (int j = 0; j < 6; ++j) {
                int h = (cg * 6 + j) * 16 + lr;
                const char* wrow = ws_c + (size_t)h * 128;
                bf16x8 w0 = *(const bf16x8*)(wrow + (((kg)     ^ (lr & 7)) * 16));
                bf16x8 w1 = *(const bf16x8*)(wrow + (((kg + 4) ^ (lr & 7)) * 16));
                acc[j] = __builtin_amdgcn_mfma_f32_16x16x32_bf16(af0, w0, acc[j], 0, 0, 0);
                acc[j] = __builtin_amdgcn_mfma_f32_16x16x32_bf16(af1, w1, acc[j], 0, 0, 0);
            }
            __builtin_amdgcn_s_setprio(0);
        }

        // rotate buffers
        char* tx = xs_c; xs_c = xs_n; xs_n = xs_nn; xs_nn = tx;
        char* tw = ws_c; ws_c = ws_n; ws_n = tw;
    }

    // C/D layout: col = lane&15 (-> h), row = kg*4 + i (-> t).
    #pragma unroll
    for (int j = 0; j < 6; ++j) {
        int p = cg * 6 + j;
        int m = p >> 2;
        int h = (p & 3) * 16 + lr;
        #pragma unroll
        for (int i = 0; i < 4; ++i) {
            int t = row0 + rg * 16 + kg * 4 + i;
            float v = acc[j][i];
            if (m == 0) {
                qb[(size_t)t * 64 + h] = (bf16_t)v;
            } else if (m == 1) {
                kb[(size_t)t * 64 + ((((h >> 3) ^ (t & 7)) << 3) | (h & 7))] = (bf16_t)v;
            } else {
                int bb = t >> 12, tt = t & 4095;
                vtb[(size_t)(bb * 64 + h) * 4096 + (tt & ~63)
                    + (((((tt >> 3) & 7) ^ (h & 7))) << 3) + (tt & 7)] = (bf16_t)v;
            }
        }
    }
#undef ISSUE_X
#undef ISSUE_W
}

// ---------------- Kernel C: causal flash attention, LDS-shared KV, 2-way KV slice ----
// 512 blocks (4 b x 128 q-tiles of 32 rows, diag-first) x 256 thr (4 waves).
// Wave w: row-group rg=w&1 (16 rows), KV-slice=w>>1 (even/odd 64-chunks).
// Chunks pair-staged once per block via global_load_lds (double-buffered, one
// barrier+vmcnt(0)/step). Pre-swizzled sources -> conflict-free ds_read_b128.
// No-max exp2 softmax; slice combine via LDS alias.
__global__ __launch_bounds__(256, 2)
void attn_kernel(const bf16_t* __restrict__ qb, const bf16_t* __restrict__ kb,
                 const bf16_t* __restrict__ vtb, float* __restrict__ out) {
    __shared__ bf16_t kvb[2][2][8192];    // [pair][chunk]: K bytes [0,8K), V bytes [8K,16K)
    __shared__ bf16_t p_lds[4][16][68];

    const int tid = threadIdx.x;
    const int w = tid >> 6, lane = tid & 63, lr = lane & 15, kg = lane >> 4;
    const int rg = w & 1, slice = w >> 1;
    const int bid = blockIdx.x;
    const int b = bid & 3;
    const int qt = 127 - (bid >> 2);      // long tiles dispatched first
    const int qrow0 = qt * 32 + rg * 16;  // this wave's 16 rows
    const size_t bT = (size_t)b * 4096;

    const int nch    = (qt + 2) >> 1;     // 64-chunks covering rows < (qt+1)*32
    const int nsteps = (nch + 1) >> 1;

#define STAGE_CHUNK(kk, pp, cc) {                                                   \
        _Pragma("unroll")                                                           \
        for (int jj = 0; jj < 2; ++jj) {                                            \
            int idx = tid + jj * 256;                                               \
            gld16((const char*)kb + (bT + (size_t)(kk) * 64) * 128 + (size_t)idx * 16, \
                  (char*)&kvb[pp][cc][0] + (size_t)idx * 16);                       \
            gld16((const char*)vtb + (size_t)(b * 64 + (idx >> 3)) * 8192           \
                      + (size_t)(kk) * 128 + (idx & 7) * 16,                        \
                  (char*)&kvb[pp][cc][4096] + (size_t)idx * 16); } }
#define STAGE_PAIR(j1) {                                                            \
        int c0 = 2 * (j1), c1 = 2 * (j1) + 1, pp = (j1) & 1;                        \
        if (c0 < nch) STAGE_CHUNK(c0, pp, 0);                                       \
        if (c1 < nch) STAGE_CHUNK(c1, pp, 1); }

    bf16x8 qf[2];
    #pragma unroll
    for (int s = 0; s < 2; ++s)
        qf[s] = *(const bf16x8*)&qb[(bT + qrow0 + lr) * 64 + s * 32 + kg * 8];

    f32x4 o_acc[4];
    float l_i[4];
    #pragma unroll
    for (int ct = 0; ct < 4; ++ct) o_acc[ct] = (f32x4){0.f, 0.f, 0.f, 0.f};
    #pragma unroll
    for (int i = 0; i < 4; ++i) l_i[i] = 0.f;

    STAGE_PAIR(0);

    for (int j = 0; j < nsteps; ++j) {
        asm volatile("s_waitcnt vmcnt(0)" ::: "memory");
        __builtin_amdgcn_s_barrier();
        asm volatile("" ::: "memory");
        if (j + 1 < nsteps) STAGE_PAIR(j + 1);

        int c = 2 * j + slice;
        if (c < nch) {                    // wave-uniform
            const bf16_t* Kt = &kvb[j & 1][slice][0];
            const bf16_t* Vt = &kvb[j & 1][slice][4096];
            int kv0 = c * 64;

            // ---- S' = Q K^T (log2-scaled), conflict-free swizzled ds_reads ----
            f32x4 sc[4];
            #pragma unroll
            for (int ct = 0; ct < 4; ++ct) sc[ct] = (f32x4){0.f, 0.f, 0.f, 0.f};
            __builtin_amdgcn_s_setprio(1);
            #pragma unroll
            for (int ct = 0; ct < 4; ++ct)
                #pragma unroll
                for (int s = 0; s < 2; ++s) {
                    bf16x8 kf = *(const bf16x8*)&Kt[(ct * 16 + lr) * 64 + (((kg + 4 * s) ^ (lr & 7)) * 8)];
                    sc[ct] = __builtin_amdgcn_mfma_f32_16x16x32_bf16(qf[s], kf, sc[ct], 0, 0, 0);
                }
            __builtin_amdgcn_s_setprio(0);

            // ---- mask (diagonal chunk only) ----
            if (kv0 + 63 > qrow0) {
                #pragma unroll
                for (int ct = 0; ct < 4; ++ct)
                    #pragma unroll
                    for (int i = 0; i < 4; ++i) {
                        int col = kv0 + ct * 16 + lr;
                        int rw  = qrow0 + kg * 4 + i;
                        if (col > rw) sc[ct][i] = -INFINITY;
                    }
            }

            // ---- exp2 + P store + per-lane l partials ----
            #pragma unroll
            for (int ct = 0; ct < 4; ++ct)
                #pragma unroll
                for (int i = 0; i < 4; ++i) {
                    float p = __builtin_amdgcn_exp2f(sc[ct][i]);
                    p_lds[w][kg * 4 + i][ct * 16 + lr] = (bf16_t)p;
                    l_i[i] += p;
                }

            // ---- O += P V ----
            bf16x8 pf[2];
            #pragma unroll
            for (int s = 0; s < 2; ++s)
                pf[s] = *(const bf16x8*)&p_lds[w][lr][s * 32 + kg * 8];
            __builtin_amdgcn_s_setprio(1);
            #pragma unroll
            for (int ct = 0; ct < 4; ++ct)
                #pragma unroll
                for (int s = 0; s < 2; ++s) {
                    bf16x8 vf = *(const bf16x8*)&Vt[(ct * 16 + lr) * 64 + (((kg + 4 * s) ^ (lr & 7)) * 8)];
                    o_acc[ct] = __builtin_amdgcn_mfma_f32_16x16x32_bf16(pf[s], vf, o_acc[ct], 0, 0, 0);
                }
            __builtin_amdgcn_s_setprio(0);
        }
    }

    // ---- epilogue: slice combine (pure sums; no-max softmax) ----
    asm volatile("s_waitcnt vmcnt(0)" ::: "memory");
    __syncthreads();

    #pragma unroll
    for (int off = 1; off < 16; off <<= 1)
        #pragma unroll
        for (int i = 0; i < 4; ++i)
            l_i[i] += __shfl_xor(l_i[i], off);

    float* co = (float*)&kvb[0][0][0];    // 32 rows x pitch 66 f32 (aliased)
    float* cl = co + 2 * 16 * 66;
    if (slice == 1) {
        #pragma unroll
        for (int ct = 0; ct < 4; ++ct)
            #pragma unroll
            for (int i = 0; i < 4; ++i)
                co[(rg * 16 + kg * 4 + i) * 66 + ct * 16 + lr] = o_acc[ct][i];
        if (lr == 0) {
            #pragma unroll
            for (int i = 0; i < 4; ++i)
                cl[rg * 16 + kg * 4 + i] = l_i[i];
        }
    }
    __syncthreads();
    if (slice == 0) {
        #pragma unroll
        for (int i = 0; i < 4; ++i) {
            int r = kg * 4 + i;
            float lv = l_i[i] + cl[rg * 16 + r];
            float inv = 1.0f / lv;
            #pragma unroll
            for (int ct = 0; ct < 4; ++ct) {
                float ov = o_acc[ct][i] + co[(rg * 16 + r) * 66 + ct * 16 + lr];
                out[(bT + qrow0 + r) * 64 + ct * 16 + lr] = ov * inv;
            }
        }
    }
#undef STAGE_CHUNK
#undef STAGE_PAIR
}

extern "C" void kernel_launch(void* const* d_in, const int* in_sizes, int n_in,
                              void* d_out, int out_size, void* d_ws, size_t ws_size,
                              hipStream_t stream) {
    const float* x  = (const float*)d_in[0];
    const float* Wq = (const float*)d_in[1];
    const float* Wk = (const float*)d_in[2];
    const float* Wv = (const float*)d_in[3];
    float* out = (float*)d_out;

    bf16_t* ws  = (bf16_t*)d_ws;
    bf16_t* wbf = ws;                    // 3*64*1024 = 196608 elems
    bf16_t* qb  = ws + 196608;           // 16384*64  = 1048576
    bf16_t* kb  = qb + 1048576;          // swizzled h-units
    bf16_t* vtb = kb + 1048576;          // [B][64][T], swizzled t-units per 64-group

    wcvt_kernel<<<768, 256, 0, stream>>>(Wq, Wk, Wv, wbf);
    qkv_proj_kernel<<<512, 256, 0, stream>>>(x, wbf, qb, kb, vtb);
    attn_kernel<<<512, 256, 0, stream>>>(qb, kb, vtb, out);
}